// Round 2
// baseline (247.808 us; speedup 1.0000x reference)
//
#include <hip/hip_runtime.h>

// SwitchTransformersLoadBalancer:
//   x: (B=64, C=8, H=256, W=256) f32, accumulator: (256, 8) f32
//   out = one_hot(argmax_c (x_c - log(mean(acc[:,c]))))   [proved R0/R1, absmax 0]
// Mandatory traffic: 128 MiB read + 128 MiB write -> ~43 us floor at 6.3 TB/s.
// R4: plain cached loads (nt-load revert) + 8x coarsening.
//   - R3 A/B was confounded: it added nt loads AND the pipeline together and
//     gained only 5.5 us. MLP arithmetic (9 KB/CU needed in flight vs 128 KB
//     available) says latency was never the limit -> suspect nt loads cost
//     L2 read-combining for zero benefit (stores already bypass via nt).
//   - 512 blocks x 256 threads, 8 float4-groups/thread, depth-2 pipeline:
//     halves per-block overhead (LDS reduce, barriers, pipeline fill/drain).

#define PLANE4 16384   // plane stride in float4 units (65536 floats)

typedef float fvec4 __attribute__((ext_vector_type(4)));

__device__ __forceinline__ void load_group(fvec4 (&u)[8], const fvec4* __restrict__ xb,
                                           int p4) {
    #pragma unroll
    for (int c = 0; c < 8; ++c)
        u[c] = xb[p4 + c * PLANE4];          // plain cached loads (L2 allocate)
}

__device__ __forceinline__ void proc_group(const fvec4 (&u)[8], const double (&ln)[8],
                                           fvec4* __restrict__ ob, int p4) {
    // f64 argmax (exact vs f32 reference; strict > = first-index ties)
    double best0 = (double)u[0].x - ln[0];
    double best1 = (double)u[0].y - ln[0];
    double best2 = (double)u[0].z - ln[0];
    double best3 = (double)u[0].w - ln[0];
    int idx0 = 0, idx1 = 0, idx2 = 0, idx3 = 0;

    #pragma unroll
    for (int c = 1; c < 8; ++c) {
        double d;
        d = (double)u[c].x - ln[c]; if (d > best0) { best0 = d; idx0 = c; }
        d = (double)u[c].y - ln[c]; if (d > best1) { best1 = d; idx1 = c; }
        d = (double)u[c].z - ln[c]; if (d > best2) { best2 = d; idx2 = c; }
        d = (double)u[c].w - ln[c]; if (d > best3) { best3 = d; idx3 = c; }
    }

    #pragma unroll
    for (int c = 0; c < 8; ++c) {
        fvec4 o;
        o.x = (idx0 == c) ? 1.0f : 0.0f;
        o.y = (idx1 == c) ? 1.0f : 0.0f;
        o.z = (idx2 == c) ? 1.0f : 0.0f;
        o.w = (idx3 == c) ? 1.0f : 0.0f;
        __builtin_nontemporal_store(o, ob + p4 + c * PLANE4);  // write-once: bypass
    }
}

__global__ __launch_bounds__(256) void fused_route_kernel(
        const float* __restrict__ x,
        const float* __restrict__ acc,
        float* __restrict__ out) {
    int t     = threadIdx.x;
    int base4 = blockIdx.x << 11;     // 2048 float4 per block (256 thr x 8 groups)
    int b     = base4 >> 14;          // 16384 float4 per plane -> block-uniform batch
    int p4    = (base4 & 16383) + t;  // group-0 float4 offset inside plane

    const fvec4* xb = (const fvec4*)(x + ((size_t)(b * 8) << 16));
    fvec4*       ob = (fvec4*)(out + ((size_t)(b * 8) << 16));

    // ---- issue group-0 streaming loads first (independent of the reduce) ----
    fvec4 ua[8], ub[8];
    load_group(ua, xb, p4);

    // ---- per-block lognorm: 8 KB accumulator -> LDS reduce -> log(mean) ----
    __shared__ double part[256];
    __shared__ double lns[8];
    {
        int c = t & 7;        // channel
        int g = t >> 3;       // row group, 0..31
        double s = 0.0;
        #pragma unroll
        for (int k = 0; k < 8; ++k) s += (double)acc[(g * 8 + k) * 8 + c];
        part[t] = s;
    }
    __syncthreads();
    if (t < 8) {
        double tot = 0.0;
        #pragma unroll
        for (int g2 = 0; g2 < 32; ++g2) tot += part[g2 * 8 + t];
        lns[t] = log(tot * (1.0 / 256.0));
    }
    __syncthreads();

    double ln[8];
    #pragma unroll
    for (int c = 0; c < 8; ++c) ln[c] = lns[c];   // same-address -> LDS broadcast

    // ---- depth-2 pipelined groups: load(g+1) in flight during proc(g) ----
    load_group(ub, xb, p4 + 1 * 256);
    proc_group(ua, ln, ob, p4 + 0 * 256);
    load_group(ua, xb, p4 + 2 * 256);
    proc_group(ub, ln, ob, p4 + 1 * 256);
    load_group(ub, xb, p4 + 3 * 256);
    proc_group(ua, ln, ob, p4 + 2 * 256);
    load_group(ua, xb, p4 + 4 * 256);
    proc_group(ub, ln, ob, p4 + 3 * 256);
    load_group(ub, xb, p4 + 5 * 256);
    proc_group(ua, ln, ob, p4 + 4 * 256);
    load_group(ua, xb, p4 + 6 * 256);
    proc_group(ub, ln, ob, p4 + 5 * 256);
    load_group(ub, xb, p4 + 7 * 256);
    proc_group(ua, ln, ob, p4 + 6 * 256);
    proc_group(ub, ln, ob, p4 + 7 * 256);
}

extern "C" void kernel_launch(void* const* d_in, const int* in_sizes, int n_in,
                              void* d_out, int out_size, void* d_ws, size_t ws_size,
                              hipStream_t stream) {
    const float* x   = (const float*)d_in[0];   // (64, 8, 256, 256)
    const float* acc = (const float*)d_in[1];   // (256, 8)
    float*       out = (float*)d_out;           // (64, 8, 256, 256)
    (void)d_ws; (void)ws_size;

    // B*H*W/4 = 1,048,576 float4; 8 float4/thread -> 512 blocks x 256 threads.
    fused_route_kernel<<<512, 256, 0, stream>>>(x, acc, out);
}

// Round 3
// 239.326 us; speedup vs baseline: 1.0354x; 1.0354x over previous
//
#include <hip/hip_runtime.h>

// SwitchTransformersLoadBalancer:
//   x: (B=64, C=8, H=256, W=256) f32, accumulator: (256, 8) f32
//   out = one_hot(argmax_c (x_c - log(mean(acc[:,c]))))   [proved R0/R1, absmax 0]
// HBM floor: ~64 MB read (half of x LLC-resident, measured R4) + 128 MB write.
// R5: restore full TLP. R4's 512-block grid (2 waves/SIMD) was latency-bound:
//   kernel 113.7 us @ 1.78 TB/s, VALUBusy 5.6%, occupancy 23% -- a depth-2
//   per-wave pipeline cannot cover queue-inflated HBM latency with 8 waves/CU.
//   R5: 2048 blocks x 256 thr x 2 groups/thread = 8 blocks/CU = 32 waves/CU
//   (VGPR 40 and LDS 2.5 KB leave the occupancy cap at the HW max).
//   Keep: hoisted group-0 loads above the reduce, depth-2 pipeline,
//   plain cached loads (LLC serves ~half of x), nontemporal stores.

#define PLANE4 16384   // plane stride in float4 units (65536 floats)

typedef float fvec4 __attribute__((ext_vector_type(4)));

__device__ __forceinline__ void load_group(fvec4 (&u)[8], const fvec4* __restrict__ xb,
                                           int p4) {
    #pragma unroll
    for (int c = 0; c < 8; ++c)
        u[c] = xb[p4 + c * PLANE4];          // plain cached loads (LLC-friendly)
}

__device__ __forceinline__ void proc_group(const fvec4 (&u)[8], const double (&ln)[8],
                                           fvec4* __restrict__ ob, int p4) {
    // f64 argmax (exact vs f32 reference; strict > = first-index ties)
    double best0 = (double)u[0].x - ln[0];
    double best1 = (double)u[0].y - ln[0];
    double best2 = (double)u[0].z - ln[0];
    double best3 = (double)u[0].w - ln[0];
    int idx0 = 0, idx1 = 0, idx2 = 0, idx3 = 0;

    #pragma unroll
    for (int c = 1; c < 8; ++c) {
        double d;
        d = (double)u[c].x - ln[c]; if (d > best0) { best0 = d; idx0 = c; }
        d = (double)u[c].y - ln[c]; if (d > best1) { best1 = d; idx1 = c; }
        d = (double)u[c].z - ln[c]; if (d > best2) { best2 = d; idx2 = c; }
        d = (double)u[c].w - ln[c]; if (d > best3) { best3 = d; idx3 = c; }
    }

    #pragma unroll
    for (int c = 0; c < 8; ++c) {
        fvec4 o;
        o.x = (idx0 == c) ? 1.0f : 0.0f;
        o.y = (idx1 == c) ? 1.0f : 0.0f;
        o.z = (idx2 == c) ? 1.0f : 0.0f;
        o.w = (idx3 == c) ? 1.0f : 0.0f;
        __builtin_nontemporal_store(o, ob + p4 + c * PLANE4);  // write-once: bypass
    }
}

__global__ __launch_bounds__(256) void fused_route_kernel(
        const float* __restrict__ x,
        const float* __restrict__ acc,
        float* __restrict__ out) {
    int t     = threadIdx.x;
    int base4 = blockIdx.x << 9;      // 512 float4 per block (256 thr x 2 groups)
    int b     = base4 >> 14;          // 16384 float4 per plane -> block-uniform batch
    int p4    = (base4 & 16383) + t;  // group-0 float4 offset inside plane

    const fvec4* xb = (const fvec4*)(x + ((size_t)(b * 8) << 16));
    fvec4*       ob = (fvec4*)(out + ((size_t)(b * 8) << 16));

    // ---- issue group-0 streaming loads first (independent of the reduce) ----
    fvec4 ua[8], ub[8];
    load_group(ua, xb, p4);

    // ---- per-block lognorm: 8 KB accumulator -> LDS reduce -> log(mean) ----
    __shared__ double part[256];
    __shared__ double lns[8];
    {
        int c = t & 7;        // channel
        int g = t >> 3;       // row group, 0..31
        double s = 0.0;
        #pragma unroll
        for (int k = 0; k < 8; ++k) s += (double)acc[(g * 8 + k) * 8 + c];
        part[t] = s;
    }
    __syncthreads();
    if (t < 8) {
        double tot = 0.0;
        #pragma unroll
        for (int g2 = 0; g2 < 32; ++g2) tot += part[g2 * 8 + t];
        lns[t] = log(tot * (1.0 / 256.0));
    }
    __syncthreads();

    double ln[8];
    #pragma unroll
    for (int c = 0; c < 8; ++c) ln[c] = lns[c];   // same-address -> LDS broadcast

    // ---- depth-2 pipeline: group-1 loads in flight during proc(group 0) ----
    load_group(ub, xb, p4 + 256);
    proc_group(ua, ln, ob, p4);
    proc_group(ub, ln, ob, p4 + 256);
}

extern "C" void kernel_launch(void* const* d_in, const int* in_sizes, int n_in,
                              void* d_out, int out_size, void* d_ws, size_t ws_size,
                              hipStream_t stream) {
    const float* x   = (const float*)d_in[0];   // (64, 8, 256, 256)
    const float* acc = (const float*)d_in[1];   // (256, 8)
    float*       out = (float*)d_out;           // (64, 8, 256, 256)
    (void)d_ws; (void)ws_size;

    // B*H*W/4 = 1,048,576 float4; 2 float4/thread -> 2048 blocks x 256 threads.
    fused_route_kernel<<<2048, 256, 0, stream>>>(x, acc, out);
}

// Round 4
// 230.540 us; speedup vs baseline: 1.0749x; 1.0381x over previous
//
#include <hip/hip_runtime.h>

// SwitchTransformersLoadBalancer:
//   x: (B=64, C=8, H=256, W=256) f32, accumulator: (256, 8) f32
//   out = one_hot(argmax_c (x_c - log(mean(acc[:,c]))))   [proved R0/R1, absmax 0]
// HBM floor: ~66 MB read (half of x LLC-resident, measured R4/R5) + 131 MB write
//   -> ~31 us at 6.3 TB/s.
// R6: barrier-free. R5's counters (2.45 TB/s, VALUBusy 8%, occ 54%) showed the
//   block barriers were the limiter: __syncthreads emits s_waitcnt vmcnt(0),
//   draining the hoisted x loads too -- every wave burst-drained twice per
//   block, coupled across 4 waves. This version has NO barriers and NO LDS:
//   each wave reduces the 8 KB accumulator itself.
//     - acc loads issued FIRST, x loads second: compiler waits become
//       vmcnt(12)/vmcnt(8) -- reduce+logs run while x is still in flight.
//     - f64 butterfly reduce via __shfl_xor (6 steps x 8 ch): bitwise-identical
//       sums on all 64 lanes, no LDS traffic.
//     - 4096 blocks x 256 thr x 1 fvec4/thread; nt stores (write-once).

#define PLANE4 16384   // plane stride in float4 units (65536 floats)

typedef float fvec4 __attribute__((ext_vector_type(4)));

__global__ __launch_bounds__(256, 4) void fused_route_kernel(
        const float* __restrict__ x,
        const float* __restrict__ acc,
        float* __restrict__ out) {
    int t    = threadIdx.x;
    int lane = t & 63;
    int tid4 = (blockIdx.x << 8) + t;   // global fvec4 index in B*H*W/4
    int b    = tid4 >> 14;              // 16384 fvec4 per plane
    int p4   = tid4 & 16383;

    const fvec4* accv = (const fvec4*)acc;          // 512 fvec4 total (8 KB)
    const fvec4* xb   = (const fvec4*)(x + ((size_t)(b * 8) << 16));
    fvec4*       ob   = (fvec4*)(out + ((size_t)(b * 8) << 16));

    // ---- issue acc loads FIRST (oldest in vmcnt queue) ----
    // lane covers rows {2l, 2l+1} (fvec4 4l..4l+3) and {128+2l, 128+2l+1}.
    fvec4 a0 = accv[4 * lane + 0];
    fvec4 a1 = accv[4 * lane + 1];
    fvec4 a2 = accv[4 * lane + 2];
    fvec4 a3 = accv[4 * lane + 3];
    fvec4 b0 = accv[256 + 4 * lane + 0];
    fvec4 b1 = accv[256 + 4 * lane + 1];
    fvec4 b2 = accv[256 + 4 * lane + 2];
    fvec4 b3 = accv[256 + 4 * lane + 3];

    // ---- then the 8 streaming x loads (stay in flight through the reduce) ----
    fvec4 u[8];
    #pragma unroll
    for (int c = 0; c < 8; ++c) u[c] = xb[p4 + c * PLANE4];

    // ---- per-lane partial sums (4 rows, all 8 channels), f64 ----
    double s[8];
    s[0] = (double)a0.x + (double)a2.x + (double)b0.x + (double)b2.x;
    s[1] = (double)a0.y + (double)a2.y + (double)b0.y + (double)b2.y;
    s[2] = (double)a0.z + (double)a2.z + (double)b0.z + (double)b2.z;
    s[3] = (double)a0.w + (double)a2.w + (double)b0.w + (double)b2.w;
    s[4] = (double)a1.x + (double)a3.x + (double)b1.x + (double)b3.x;
    s[5] = (double)a1.y + (double)a3.y + (double)b1.y + (double)b3.y;
    s[6] = (double)a1.z + (double)a3.z + (double)b1.z + (double)b3.z;
    s[7] = (double)a1.w + (double)a3.w + (double)b1.w + (double)b3.w;

    // ---- wave butterfly: full 256-row sum per channel, identical on all lanes ----
    #pragma unroll
    for (int m = 1; m < 64; m <<= 1) {
        #pragma unroll
        for (int c = 0; c < 8; ++c) s[c] += __shfl_xor(s[c], m, 64);
    }

    // ---- lognorm (overlapped with x loads still in flight) ----
    double ln[8];
    #pragma unroll
    for (int c = 0; c < 8; ++c) ln[c] = log(s[c] * (1.0 / 256.0));

    // ---- f64 argmax (exact vs f32 reference; strict > = first-index ties) ----
    double best0 = (double)u[0].x - ln[0];
    double best1 = (double)u[0].y - ln[0];
    double best2 = (double)u[0].z - ln[0];
    double best3 = (double)u[0].w - ln[0];
    int idx0 = 0, idx1 = 0, idx2 = 0, idx3 = 0;

    #pragma unroll
    for (int c = 1; c < 8; ++c) {
        double d;
        d = (double)u[c].x - ln[c]; if (d > best0) { best0 = d; idx0 = c; }
        d = (double)u[c].y - ln[c]; if (d > best1) { best1 = d; idx1 = c; }
        d = (double)u[c].z - ln[c]; if (d > best2) { best2 = d; idx2 = c; }
        d = (double)u[c].w - ln[c]; if (d > best3) { best3 = d; idx3 = c; }
    }

    // ---- nontemporal one-hot stores (write-once, bypass LLC alloc) ----
    #pragma unroll
    for (int c = 0; c < 8; ++c) {
        fvec4 o;
        o.x = (idx0 == c) ? 1.0f : 0.0f;
        o.y = (idx1 == c) ? 1.0f : 0.0f;
        o.z = (idx2 == c) ? 1.0f : 0.0f;
        o.w = (idx3 == c) ? 1.0f : 0.0f;
        __builtin_nontemporal_store(o, ob + p4 + c * PLANE4);
    }
}

extern "C" void kernel_launch(void* const* d_in, const int* in_sizes, int n_in,
                              void* d_out, int out_size, void* d_ws, size_t ws_size,
                              hipStream_t stream) {
    const float* x   = (const float*)d_in[0];   // (64, 8, 256, 256)
    const float* acc = (const float*)d_in[1];   // (256, 8)
    float*       out = (float*)d_out;           // (64, 8, 256, 256)
    (void)d_ws; (void)ws_size;

    // B*H*W/4 = 1,048,576 fvec4; 1 fvec4/thread -> 4096 blocks x 256 threads.
    fused_route_kernel<<<4096, 256, 0, stream>>>(x, acc, out);
}